// Round 6
// baseline (19355.186 us; speedup 1.0000x reference)
//
#include <hip/hip_runtime.h>

typedef _Float16 f16;
typedef _Float16 f16x8 __attribute__((ext_vector_type(8)));
typedef float f32x4 __attribute__((ext_vector_type(4)));

#define H_    256
#define TB_   128     // batch rows per workgroup
#define NT_   1024    // 16 waves
#define NBLK_ 256     // one WG per CU, co-resident (LDS-forced 1 WG/CU)
#define SORB_ 64
#define SLOT_ 8192    // 32 rows * 256 cols f16 = 16 KB

#define MFMA16(a, b, c) __builtin_amdgcn_mfma_f32_16x16x32_f16((a), (b), (c), 0, 0, 0)
#define UNR _Pragma("unroll")

__device__ __forceinline__ float sigm(float v) { return 1.0f / (1.0f + __expf(-v)); }
__device__ __forceinline__ float tanh_fast(float v) {
  float a = fabsf(v);
  float e = __expf(-2.0f * a);
  float t = (1.0f - e) / (1.0f + e);
  return copysignf(t, v);
}
__device__ __forceinline__ int lswz(int lrow, int col) {
  return lrow * H_ + (col ^ ((lrow & 7) << 3));
}

// grid phase-lock barrier (perf-only: correctness never depends on it).
// Two-counter generation barrier, device scope, bounded spin as hang insurance.
__device__ __forceinline__ void gbar(unsigned* cnt, unsigned* gen) {
  __syncthreads();
  if (threadIdx.x == 0) {
    unsigned g = __hip_atomic_load(gen, __ATOMIC_RELAXED, __HIP_MEMORY_SCOPE_AGENT);
    if (__hip_atomic_fetch_add(cnt, 1u, __ATOMIC_ACQ_REL, __HIP_MEMORY_SCOPE_AGENT) == NBLK_ - 1u) {
      __hip_atomic_store(cnt, 0u, __ATOMIC_RELAXED, __HIP_MEMORY_SCOPE_AGENT);
      __hip_atomic_fetch_add(gen, 1u, __ATOMIC_RELEASE, __HIP_MEMORY_SCOPE_AGENT);
    } else {
      int spins = 0;
      while (__hip_atomic_load(gen, __ATOMIC_ACQUIRE, __HIP_MEMORY_SCOPE_AGENT) == g) {
        __builtin_amdgcn_s_sleep(2);
        if (++spins > 16384) break;   // degraded mode: proceed unlocked
      }
    }
  }
  __syncthreads();
}

// fp32 -> f16 weights [whh0 | wih1 | whh1] each [768][256]; also zero barrier vars
__global__ void wcvt(const float* __restrict__ a, const float* __restrict__ b,
                     const float* __restrict__ c, f16* __restrict__ o,
                     unsigned* __restrict__ bar) {
  int i = blockIdx.x * 256 + threadIdx.x;
  const int n = 768 * 256;
  if (i < n) {
    o[i]         = (f16)a[i];
    o[n + i]     = (f16)b[i];
    o[2 * n + i] = (f16)c[i];
  }
  if (blockIdx.x == 0 && threadIdx.x < 2) bar[threadIdx.x] = 0u;
}

__global__ __launch_bounds__(NT_, 4) void rnnwf(
    const int* __restrict__ x,
    const float* __restrict__ w_ih0, const float* __restrict__ b_ih0,
    const float* __restrict__ b_hh0, const float* __restrict__ b_ih1,
    const float* __restrict__ b_hh1, const float* __restrict__ w_amp,
    const float* __restrict__ b_amp, const f16* __restrict__ W16,
    unsigned* __restrict__ bar, float* __restrict__ out)
{
  __shared__ __align__(16) f16 hall[9 * SLOT_];   // 144 KB: h0 q0..3, h1 q0..3, spare
  __shared__ f16 wampLh[512];
  __shared__ unsigned short bitsL[TB_ * 4];

  const int tid  = threadIdx.x;
  const int wave = tid >> 6;                 // 0..15
  const int lane = tid & 63;
  const int l15  = lane & 15;
  const int lg   = lane >> 4;                // 0..3
  const int col  = wave * 16 + l15;          // fixed hidden column per thread
  const int rowbase = blockIdx.x * TB_;

  // ---- one-time setup ----
  for (int j = tid; j < 512; j += NT_) wampLh[j] = (f16)w_amp[j];
  if (tid < 512) {
    int row = tid >> 2, q = tid & 3;
    const int* xp = x + (size_t)(rowbase + row) * SORB_ + q * 16;
    unsigned m = 0;
    #pragma unroll
    for (int i = 0; i < 16; ++i) m |= (unsigned)(xp[i] & 1) << i;
    bitsL[row * 4 + q] = (unsigned short)m;
  }
  for (int i = tid; i < 9 * SLOT_; i += NT_) hall[i] = (f16)0.f;

  // per-thread L0 gate tables (col-indexed) and L1 biases, all in registers
  const float baseR = b_ih0[col]       + b_hh0[col];
  const float baseZ = b_ih0[256 + col] + b_hh0[256 + col];
  const float baseN = b_ih0[512 + col];
  const float wR0 = w_ih0[2 * col + 0],         wR1 = w_ih0[2 * col + 1];
  const float wZ0 = w_ih0[2 * (256 + col) + 0], wZ1 = w_ih0[2 * (256 + col) + 1];
  const float wN0 = w_ih0[2 * (512 + col) + 0], wN1 = w_ih0[2 * (512 + col) + 1];
  const float bhh0n_c = b_hh0[512 + col];
  const float b1r_c  = b_ih1[col]       + b_hh1[col];
  const float b1z_c  = b_ih1[256 + col] + b_hh1[256 + col];
  const float b1ni_c = b_ih1[512 + col];
  const float b1nh_c = b_hh1[512 + col];
  const float ba0 = b_amp[0], ba1 = b_amp[1];
  __syncthreads();

  float prob = 1.0f;
  const f16* Wih1 = W16 + 768 * 256;
  const f16* Whh1 = W16 + 2 * 768 * 256;

  int bh0[4] = {0, SLOT_, 2 * SLOT_, 3 * SLOT_};
  int bh1[4] = {4 * SLOT_, 5 * SLOT_, 6 * SLOT_, 7 * SLOT_};
  int sp = 8 * SLOT_;

  for (int t = -1; t < SORB_; ++t) {
    gbar(bar, bar + 1);   // phase-lock all 256 WGs to the same weight region

    // ======== layer 0: 4 quarter-phases, read bh0[q] -> write sp ========
    UNR for (int q = 0; q < 4; ++q) {
      const int src = bh0[q], tgt = sp;
      f32x4 aR[2], aZ[2], aN[2];
      UNR for (int m = 0; m < 2; ++m) { aR[m] = (f32x4){0,0,0,0}; aZ[m] = aR[m]; aN[m] = aR[m]; }
      UNR for (int kt = 0; kt < 8; ++kt) {
        const int k0 = kt * 32 + lg * 8;
        const f16* wb = W16 + col * 256 + k0;
        f16x8 Br = *(const f16x8*)(wb);
        f16x8 Bz = *(const f16x8*)(wb + 65536);
        f16x8 Bn = *(const f16x8*)(wb + 131072);
        UNR for (int m = 0; m < 2; ++m) {
          f16x8 A = *(const f16x8*)&hall[src + lswz(m * 16 + l15, k0)];
          aR[m] = MFMA16(A, Br, aR[m]);
          aZ[m] = MFMA16(A, Bz, aZ[m]);
          aN[m] = MFMA16(A, Bn, aN[m]);
        }
      }
      UNR for (int m = 0; m < 2; ++m) {
        UNR for (int e = 0; e < 4; ++e) {
          const int lrow = m * 16 + lg * 4 + e;
          const int grow = q * 32 + lrow;
          float giR = baseR, giZ = baseZ, giN = baseN;
          if (t >= 0) {
            const int bit = (bitsL[grow * 4 + (t >> 4)] >> (t & 15)) & 1;
            giR += bit ? wR1 : wR0;
            giZ += bit ? wZ1 : wZ0;
            giN += bit ? wN1 : wN0;
          }
          float r  = sigm(aR[m][e] + giR);
          float z  = sigm(aZ[m][e] + giZ);
          float n  = tanh_fast(giN + r * (aN[m][e] + bhh0n_c));
          float ho = (float)hall[src + lswz(lrow, col)];
          hall[tgt + lswz(lrow, col)] = (f16)((1.0f - z) * n + z * ho);
        }
      }
      __syncthreads();
      int tmp = bh0[q]; bh0[q] = sp; sp = tmp;
    }

    // ======== layer 1: 4 quarter-phases, read bh0[q](h0') + bh1[q](h1) -> write sp ========
    UNR for (int q = 0; q < 4; ++q) {
      const int s0 = bh0[q], s1 = bh1[q], tgt = sp;
      f32x4 aR[2], aZ[2], aNi[2], aNh[2];
      UNR for (int m = 0; m < 2; ++m) { aR[m] = (f32x4){0,0,0,0}; aZ[m] = aR[m]; aNi[m] = aR[m]; aNh[m] = aR[m]; }
      UNR for (int kt = 0; kt < 8; ++kt) {
        const int k0 = kt * 32 + lg * 8;
        const f16* wi = Wih1 + col * 256 + k0;
        const f16* wh = Whh1 + col * 256 + k0;
        f16x8 BiR = *(const f16x8*)(wi);
        f16x8 BiZ = *(const f16x8*)(wi + 65536);
        f16x8 BiN = *(const f16x8*)(wi + 131072);
        f16x8 BhR = *(const f16x8*)(wh);
        f16x8 BhZ = *(const f16x8*)(wh + 65536);
        f16x8 BhN = *(const f16x8*)(wh + 131072);
        UNR for (int m = 0; m < 2; ++m) {
          f16x8 A0 = *(const f16x8*)&hall[s0 + lswz(m * 16 + l15, k0)];
          f16x8 A1 = *(const f16x8*)&hall[s1 + lswz(m * 16 + l15, k0)];
          aR[m]  = MFMA16(A0, BiR, aR[m]);  aR[m] = MFMA16(A1, BhR, aR[m]);
          aZ[m]  = MFMA16(A0, BiZ, aZ[m]);  aZ[m] = MFMA16(A1, BhZ, aZ[m]);
          aNi[m] = MFMA16(A0, BiN, aNi[m]);
          aNh[m] = MFMA16(A1, BhN, aNh[m]);
        }
      }
      UNR for (int m = 0; m < 2; ++m) {
        UNR for (int e = 0; e < 4; ++e) {
          const int lrow = m * 16 + lg * 4 + e;
          float r = sigm(aR[m][e] + b1r_c);
          float z = sigm(aZ[m][e] + b1z_c);
          float n = tanh_fast(aNi[m][e] + b1ni_c + r * (aNh[m][e] + b1nh_c));
          float ho = (float)hall[s1 + lswz(lrow, col)];
          hall[tgt + lswz(lrow, col)] = (f16)((1.0f - z) * n + z * ho);
        }
      }
      __syncthreads();
      int tmp = bh1[q]; bh1[q] = sp; sp = tmp;
    }

    // ======== amplitude head (reads h1' in bh1[*]) ========
    if (t >= 0) {
      const int row = tid >> 3;            // 128 rows, 8 threads each
      const int t8  = tid & 7;
      const int qh  = row >> 5;
      const int lrow = row & 31;
      const int hb = qh == 0 ? bh1[0] : qh == 1 ? bh1[1] : qh == 2 ? bh1[2] : bh1[3];
      float d0 = 0.f, d1 = 0.f;
      #pragma unroll
      for (int j = 0; j < 4; ++j) {
        const int k0 = t8 * 32 + j * 8;
        f16x8 hv = *(const f16x8*)&hall[hb + lswz(lrow, k0)];
        #pragma unroll
        for (int i = 0; i < 8; ++i) {
          float hf = (float)hv[i];
          d0 = fmaf(hf, (float)wampLh[k0 + i], d0);
          d1 = fmaf(hf, (float)wampLh[256 + k0 + i], d1);
        }
      }
      d0 += __shfl_xor(d0, 1); d0 += __shfl_xor(d0, 2); d0 += __shfl_xor(d0, 4);
      d1 += __shfl_xor(d1, 1); d1 += __shfl_xor(d1, 2); d1 += __shfl_xor(d1, 4);
      const int bit = (bitsL[row * 4 + (t >> 4)] >> (t & 15)) & 1;
      float diff = (d0 + ba0) - (d1 + ba1);
      if (bit) diff = -diff;
      prob *= 1.0f / (1.0f + __expf(-diff));
    }
  }

  if ((tid & 7) == 0) out[rowbase + (tid >> 3)] = sqrtf(prob);
}

extern "C" void kernel_launch(void* const* d_in, const int* in_sizes, int n_in,
                              void* d_out, int out_size, void* d_ws, size_t ws_size,
                              hipStream_t stream) {
  const int*   x     = (const int*)d_in[0];
  const float* w_ih0 = (const float*)d_in[1];
  const float* w_hh0 = (const float*)d_in[2];
  const float* b_ih0 = (const float*)d_in[3];
  const float* b_hh0 = (const float*)d_in[4];
  const float* w_ih1 = (const float*)d_in[5];
  const float* w_hh1 = (const float*)d_in[6];
  const float* b_ih1 = (const float*)d_in[7];
  const float* b_hh1 = (const float*)d_in[8];
  const float* w_amp = (const float*)d_in[9];
  const float* b_amp = (const float*)d_in[10];
  (void)in_sizes; (void)n_in; (void)out_size; (void)ws_size;

  f16* W16 = (f16*)d_ws;                          // 1.18 MB
  unsigned* bar = (unsigned*)((char*)d_ws + 3 * 768 * 256 * sizeof(f16));
  hipLaunchKernelGGL(wcvt, dim3(768), dim3(256), 0, stream, w_hh0, w_ih1, w_hh1, W16, bar);
  hipLaunchKernelGGL(rnnwf, dim3(NBLK_), dim3(NT_), 0, stream,
                     x, w_ih0, b_ih0, b_hh0, b_ih1, b_hh1, w_amp, b_amp, W16, bar,
                     (float*)d_out);
}

// Round 7
// 5748.502 us; speedup vs baseline: 3.3670x; 3.3670x over previous
//
#include <hip/hip_runtime.h>

typedef _Float16 f16;
typedef _Float16 f16x8 __attribute__((ext_vector_type(8)));
typedef float f32x4 __attribute__((ext_vector_type(4)));

#define H_    256
#define TB_   64      // batch rows per workgroup
#define NT_   1024    // 16 waves, 4 per SIMD
#define SORB_ 64
#define SLOT_ 8192    // 32 rows * 256 cols f16 = 16 KB; a pair (64 rows) = 2 slots

#define MFMA16(a, b, c) __builtin_amdgcn_mfma_f32_16x16x32_f16((a), (b), (c), 0, 0, 0)
#define UNR _Pragma("unroll")

__device__ __forceinline__ float sigm(float v) { return 1.0f / (1.0f + __expf(-v)); }
__device__ __forceinline__ float tanh_fast(float v) {
  float a = fabsf(v);
  float e = __expf(-2.0f * a);
  float t = (1.0f - e) / (1.0f + e);
  return copysignf(t, v);
}
// XOR-swizzle within a 32-row slot (f16 units, 16B granule)
__device__ __forceinline__ int lswz(int lrow, int col) {
  return lrow * H_ + (col ^ ((lrow & 7) << 3));
}

// fp32 -> f16 weight conversion: [whh0 | wih1 | whh1], each [768][256] row-major
__global__ void wcvt(const float* __restrict__ a, const float* __restrict__ b,
                     const float* __restrict__ c, f16* __restrict__ o) {
  int i = blockIdx.x * 256 + threadIdx.x;
  const int n = 768 * 256;
  if (i < n) {
    o[i]         = (f16)a[i];
    o[n + i]     = (f16)b[i];
    o[2 * n + i] = (f16)c[i];
  }
}

__global__ __launch_bounds__(NT_, 4) void rnnwf(
    const int* __restrict__ x,
    const float* __restrict__ w_ih0, const float* __restrict__ b_ih0,
    const float* __restrict__ b_hh0, const float* __restrict__ b_ih1,
    const float* __restrict__ b_hh1, const float* __restrict__ w_amp,
    const float* __restrict__ b_amp, const f16* __restrict__ W16,
    float* __restrict__ out)
{
  __shared__ __align__(16) f16 hall[6 * SLOT_];  // 96 KB: 3 pairs of 64 rows
  __shared__ float gi0T[3 * 768];   // [prime, bit0, bit1][768]; b_hh0 folded for j<512
  __shared__ float wampL[512];
  __shared__ unsigned short bitsL[TB_ * 4];

  const int tid  = threadIdx.x;
  const int wave = tid >> 6;                  // 0..15
  const int lane = tid & 63;
  const int l15  = lane & 15;
  const int lg   = lane >> 4;                 // 0..3
  const int col  = wave * 16 + l15;           // fixed hidden column per thread
  const int rowbase = blockIdx.x * TB_;

  // ---- one-time setup ----
  for (int j = tid; j < 768; j += NT_) {
    float bi = b_ih0[j], bh = b_hh0[j];
    float base = bi + (j < 512 ? bh : 0.0f);
    gi0T[j]        = base;
    gi0T[768 + j]  = base + w_ih0[2 * j + 0];
    gi0T[1536 + j] = base + w_ih0[2 * j + 1];
  }
  for (int j = tid; j < 512; j += NT_) wampL[j] = w_amp[j];
  if (tid < 256) {
    int row = tid >> 2, q = tid & 3;
    const int* xp = x + (size_t)(rowbase + row) * SORB_ + q * 16;
    unsigned m = 0;
    #pragma unroll
    for (int i = 0; i < 16; ++i) m |= (unsigned)(xp[i] & 1) << i;
    bitsL[row * 4 + q] = (unsigned short)m;
  }
  for (int i = tid; i < 6 * SLOT_; i += NT_) hall[i] = (f16)0.f;

  // per-thread bias constants
  const float bhh0n_c = b_hh0[512 + col];
  const float b1r_c   = b_ih1[col]       + b_hh1[col];
  const float b1z_c   = b_ih1[256 + col] + b_hh1[256 + col];
  const float b1ni_c  = b_ih1[512 + col];
  const float b1nh_c  = b_hh1[512 + col];
  const float ba0 = b_amp[0], ba1 = b_amp[1];
  __syncthreads();

  float prob = 1.0f;
  const f16* Wih1 = W16 + 768 * 256;
  const f16* Whh1 = W16 + 2 * 768 * 256;
  const f16* p0base = W16  + col * 256;
  const f16* pibase = Wih1 + col * 256;
  const f16* phbase = Whh1 + col * 256;

  int pa = 0, pb = 2 * SLOT_, pc = 4 * SLOT_;   // h0_cur, h1_cur, free

  for (int t = -1; t < SORB_; ++t) {
    // ================= layer 0: read pa -> write pc =================
    {
      f32x4 aR[4], aZ[4], aN[4];
      UNR for (int m = 0; m < 4; ++m) { aR[m] = (f32x4){0,0,0,0}; aZ[m] = aR[m]; aN[m] = aR[m]; }
      #pragma unroll 2
      for (int kt = 0; kt < 8; ++kt) {
        const int k0 = kt * 32 + lg * 8;
        f16x8 Br = *(const f16x8*)(p0base + k0);
        f16x8 Bz = *(const f16x8*)(p0base + 65536 + k0);
        f16x8 Bn = *(const f16x8*)(p0base + 131072 + k0);
        UNR for (int m = 0; m < 4; ++m) {
          f16x8 A = *(const f16x8*)&hall[pa + (m >> 1) * SLOT_ + lswz((m & 1) * 16 + l15, k0)];
          aR[m] = MFMA16(A, Br, aR[m]);
          aZ[m] = MFMA16(A, Bz, aZ[m]);
          aN[m] = MFMA16(A, Bn, aN[m]);
        }
      }
      UNR for (int m = 0; m < 4; ++m) {
        UNR for (int e = 0; e < 4; ++e) {
          const int lrow = (m & 1) * 16 + lg * 4 + e;
          const int grow = m * 16 + lg * 4 + e;
          int cse = 0;
          if (t >= 0) cse = 1 + ((bitsL[grow * 4 + (t >> 4)] >> (t & 15)) & 1);
          const float* gt = &gi0T[cse * 768];
          float r  = sigm(aR[m][e] + gt[col]);
          float z  = sigm(aZ[m][e] + gt[256 + col]);
          float n  = tanh_fast(gt[512 + col] + r * (aN[m][e] + bhh0n_c));
          float ho = (float)hall[pa + (m >> 1) * SLOT_ + lswz(lrow, col)];
          hall[pc + (m >> 1) * SLOT_ + lswz(lrow, col)] = (f16)((1.0f - z) * n + z * ho);
        }
      }
    }
    __syncthreads();

    // ================= layer 1: read pc (h0') + pb (h1) -> write pa =================
    {
      // ---- pass 1: r,z gates (both ih and hh contributions chained) ----
      f32x4 aR[4], aZ[4];
      UNR for (int m = 0; m < 4; ++m) { aR[m] = (f32x4){0,0,0,0}; aZ[m] = aR[m]; }
      #pragma unroll 2
      for (int kt = 0; kt < 8; ++kt) {
        const int k0 = kt * 32 + lg * 8;
        f16x8 BiR = *(const f16x8*)(pibase + k0);
        f16x8 BiZ = *(const f16x8*)(pibase + 65536 + k0);
        f16x8 BhR = *(const f16x8*)(phbase + k0);
        f16x8 BhZ = *(const f16x8*)(phbase + 65536 + k0);
        UNR for (int m = 0; m < 4; ++m) {
          f16x8 A0 = *(const f16x8*)&hall[pc + (m >> 1) * SLOT_ + lswz((m & 1) * 16 + l15, k0)];
          f16x8 A1 = *(const f16x8*)&hall[pb + (m >> 1) * SLOT_ + lswz((m & 1) * 16 + l15, k0)];
          aR[m] = MFMA16(A0, BiR, aR[m]);  aR[m] = MFMA16(A1, BhR, aR[m]);
          aZ[m] = MFMA16(A0, BiZ, aZ[m]);  aZ[m] = MFMA16(A1, BhZ, aZ[m]);
        }
      }
      f32x4 rv[4], zv[4];
      UNR for (int m = 0; m < 4; ++m)
        UNR for (int e = 0; e < 4; ++e) {
          rv[m][e] = sigm(aR[m][e] + b1r_c);
          zv[m][e] = sigm(aZ[m][e] + b1z_c);
        }
      // ---- pass 2: n gate ----
      f32x4 aNi[4], aNh[4];
      UNR for (int m = 0; m < 4; ++m) { aNi[m] = (f32x4){0,0,0,0}; aNh[m] = aNi[m]; }
      #pragma unroll 2
      for (int kt = 0; kt < 8; ++kt) {
        const int k0 = kt * 32 + lg * 8;
        f16x8 BiN = *(const f16x8*)(pibase + 131072 + k0);
        f16x8 BhN = *(const f16x8*)(phbase + 131072 + k0);
        UNR for (int m = 0; m < 4; ++m) {
          f16x8 A0 = *(const f16x8*)&hall[pc + (m >> 1) * SLOT_ + lswz((m & 1) * 16 + l15, k0)];
          f16x8 A1 = *(const f16x8*)&hall[pb + (m >> 1) * SLOT_ + lswz((m & 1) * 16 + l15, k0)];
          aNi[m] = MFMA16(A0, BiN, aNi[m]);
          aNh[m] = MFMA16(A1, BhN, aNh[m]);
        }
      }
      UNR for (int m = 0; m < 4; ++m) {
        UNR for (int e = 0; e < 4; ++e) {
          const int lrow = (m & 1) * 16 + lg * 4 + e;
          float n  = tanh_fast(aNi[m][e] + b1ni_c + rv[m][e] * (aNh[m][e] + b1nh_c));
          float z  = zv[m][e];
          float ho = (float)hall[pb + (m >> 1) * SLOT_ + lswz(lrow, col)];
          hall[pa + (m >> 1) * SLOT_ + lswz(lrow, col)] = (f16)((1.0f - z) * n + z * ho);
        }
      }
    }
    __syncthreads();

    // ================= amplitude head (reads pa = h1_new) =================
    if (t >= 0) {
      const int row = tid >> 4;            // 64 rows, 16 threads each
      const int t16 = tid & 15;
      float d0 = 0.f, d1 = 0.f;
      #pragma unroll
      for (int j = 0; j < 2; ++j) {
        const int k0 = t16 * 16 + j * 8;
        f16x8 hv = *(const f16x8*)&hall[pa + (row >> 5) * SLOT_ + lswz(row & 31, k0)];
        #pragma unroll
        for (int i = 0; i < 8; ++i) {
          float hf = (float)hv[i];
          d0 = fmaf(hf, wampL[k0 + i], d0);
          d1 = fmaf(hf, wampL[256 + k0 + i], d1);
        }
      }
      d0 += __shfl_xor(d0, 1); d0 += __shfl_xor(d0, 2);
      d0 += __shfl_xor(d0, 4); d0 += __shfl_xor(d0, 8);
      d1 += __shfl_xor(d1, 1); d1 += __shfl_xor(d1, 2);
      d1 += __shfl_xor(d1, 4); d1 += __shfl_xor(d1, 8);
      const int bit = (bitsL[row * 4 + (t >> 4)] >> (t & 15)) & 1;
      float diff = (d0 + ba0) - (d1 + ba1);
      if (bit) diff = -diff;
      prob *= 1.0f / (1.0f + __expf(-diff));
    }

    // rotate pairs: h0_cur := pc, h1_cur := pa, free := pb
    int tmp = pa; pa = pc; pc = pb; pb = tmp;
  }

  if ((tid & 15) == 0) out[rowbase + (tid >> 4)] = sqrtf(prob);
}

extern "C" void kernel_launch(void* const* d_in, const int* in_sizes, int n_in,
                              void* d_out, int out_size, void* d_ws, size_t ws_size,
                              hipStream_t stream) {
  const int*   x     = (const int*)d_in[0];
  const float* w_ih0 = (const float*)d_in[1];
  const float* w_hh0 = (const float*)d_in[2];
  const float* b_ih0 = (const float*)d_in[3];
  const float* b_hh0 = (const float*)d_in[4];
  const float* w_ih1 = (const float*)d_in[5];
  const float* w_hh1 = (const float*)d_in[6];
  const float* b_ih1 = (const float*)d_in[7];
  const float* b_hh1 = (const float*)d_in[8];
  const float* w_amp = (const float*)d_in[9];
  const float* b_amp = (const float*)d_in[10];
  (void)in_sizes; (void)n_in; (void)out_size; (void)ws_size;

  f16* W16 = (f16*)d_ws;   // 3*768*256*2 = 1.18 MB of workspace
  hipLaunchKernelGGL(wcvt, dim3(768), dim3(256), 0, stream, w_hh0, w_ih1, w_hh1, W16);
  hipLaunchKernelGGL(rnnwf, dim3(32768 / TB_), dim3(NT_), 0, stream,
                     x, w_ih0, b_ih0, b_hh0, b_ih1, b_hh1, w_amp, b_amp, W16,
                     (float*)d_out);
}

// Round 8
// 5106.701 us; speedup vs baseline: 3.7902x; 1.1257x over previous
//
#include <hip/hip_runtime.h>

typedef _Float16 f16;
typedef _Float16 f16x8 __attribute__((ext_vector_type(8)));
typedef float f32x4 __attribute__((ext_vector_type(4)));

#define H_    256
#define TB_   64      // batch rows per workgroup
#define NT_   1024    // 16 waves, 4 per SIMD
#define SORB_ 64
#define SLOT_ 8192    // 32 rows * 256 cols f16 = 16 KB; a pair (64 rows) = 2 slots

#define MFMA16(a, b, c) __builtin_amdgcn_mfma_f32_16x16x32_f16((a), (b), (c), 0, 0, 0)
#define UNR _Pragma("unroll")

// fast activations: native v_exp_f32 (computes 2^x) + v_rcp_f32; rel err ~1e-7,
// negligible vs the f16-weight quantization (~1e-3 budget)
__device__ __forceinline__ float sigm(float v) {
  return __builtin_amdgcn_rcpf(1.0f + __builtin_amdgcn_exp2f(v * -1.442695040888963f));
}
__device__ __forceinline__ float tanh_fast(float v) {
  float a = fabsf(v);
  float e = __builtin_amdgcn_exp2f(a * -2.885390081777927f);
  float t = (1.0f - e) * __builtin_amdgcn_rcpf(1.0f + e);
  return copysignf(t, v);
}
// XOR-swizzle within a 32-row slot (f16 units, 16B granule)
__device__ __forceinline__ int lswz(int lrow, int col) {
  return lrow * H_ + (col ^ ((lrow & 7) << 3));
}

// fp32 -> f16 weight conversion: [whh0 | wih1 | whh1], each [768][256] row-major
__global__ void wcvt(const float* __restrict__ a, const float* __restrict__ b,
                     const float* __restrict__ c, f16* __restrict__ o) {
  int i = blockIdx.x * 256 + threadIdx.x;
  const int n = 768 * 256;
  if (i < n) {
    o[i]         = (f16)a[i];
    o[n + i]     = (f16)b[i];
    o[2 * n + i] = (f16)c[i];
  }
}

__global__ __launch_bounds__(NT_, 4) void rnnwf(
    const int* __restrict__ x,
    const float* __restrict__ w_ih0, const float* __restrict__ b_ih0,
    const float* __restrict__ b_hh0, const float* __restrict__ b_ih1,
    const float* __restrict__ b_hh1, const float* __restrict__ w_amp,
    const float* __restrict__ b_amp, const f16* __restrict__ W16,
    float* __restrict__ out)
{
  __shared__ __align__(16) f16 hall[6 * SLOT_];  // 96 KB: 3 pairs of 64 rows
  __shared__ float wampL[512];
  __shared__ unsigned short bitsL[TB_ * 4];
  __shared__ unsigned long long bitsT[SORB_];    // bit r of bitsT[t] = x[row r][t]

  const int tid  = threadIdx.x;
  const int wave = tid >> 6;                  // 0..15
  const int lane = tid & 63;
  const int l15  = lane & 15;
  const int lg   = lane >> 4;                 // 0..3
  const int lg4  = lg << 2;
  const int col  = wave * 16 + l15;           // fixed hidden column per thread
  const int rowbase = blockIdx.x * TB_;

  // ---- one-time setup ----
  for (int j = tid; j < 512; j += NT_) wampL[j] = w_amp[j];
  if (tid < 256) {
    int row = tid >> 2, q = tid & 3;
    const int* xp = x + (size_t)(rowbase + row) * SORB_ + q * 16;
    unsigned m = 0;
    #pragma unroll
    for (int i = 0; i < 16; ++i) m |= (unsigned)(xp[i] & 1) << i;
    bitsL[row * 4 + q] = (unsigned short)m;
  }
  for (int i = tid; i < 6 * SLOT_; i += NT_) hall[i] = (f16)0.f;

  // per-thread L0 gate tables (step-invariant, register-resident)
  const float baseR = b_ih0[col]       + b_hh0[col];
  const float baseZ = b_ih0[256 + col] + b_hh0[256 + col];
  const float baseN = b_ih0[512 + col];
  const float wR0 = w_ih0[2 * col + 0],         wR1 = w_ih0[2 * col + 1];
  const float wZ0 = w_ih0[2 * (256 + col) + 0], wZ1 = w_ih0[2 * (256 + col) + 1];
  const float wN0 = w_ih0[2 * (512 + col) + 0], wN1 = w_ih0[2 * (512 + col) + 1];
  const float sumR0 = baseR + wR0, dR = wR1 - wR0;
  const float sumZ0 = baseZ + wZ0, dZ = wZ1 - wZ0;
  const float sumN0 = baseN + wN0, dN = wN1 - wN0;
  const float bhh0n_c = b_hh0[512 + col];
  const float b1r_c   = b_ih1[col]       + b_hh1[col];
  const float b1z_c   = b_ih1[256 + col] + b_hh1[256 + col];
  const float b1ni_c  = b_ih1[512 + col];
  const float b1nh_c  = b_hh1[512 + col];
  const float ba0 = b_amp[0], ba1 = b_amp[1];
  __syncthreads();

  // transpose bit matrix: bitsT[t] holds bit-per-row for step t (broadcast read later)
  if (tid < SORB_) {
    unsigned long long mk = 0ull;
    const int q = tid >> 4, sh = tid & 15;
    #pragma unroll 4
    for (int r = 0; r < TB_; ++r)
      mk |= (unsigned long long)((bitsL[r * 4 + q] >> sh) & 1) << r;
    bitsT[tid] = mk;
  }
  __syncthreads();

  float prob = 1.0f;
  const f16* Wih1 = W16 + 768 * 256;
  const f16* Whh1 = W16 + 2 * 768 * 256;
  const f16* p0base = W16  + col * 256;
  const f16* pibase = Wih1 + col * 256;
  const f16* phbase = Whh1 + col * 256;

  // head constants
  const int hrow = tid >> 4;            // 0..63
  const int hsh  = hrow & 31;
  const bool hhi = hrow >= 32;

  int pa = 0, pb = 2 * SLOT_, pc = 4 * SLOT_;   // h0_cur, h1_cur, free

  for (int t = -1; t < SORB_; ++t) {
    unsigned lo32 = 0u, hi32 = 0u;
    if (t >= 0) {
      unsigned long long mk = bitsT[t];        // uniform address -> broadcast
      lo32 = (unsigned)mk; hi32 = (unsigned)(mk >> 32);
    }

    // ================= layer 0: read pa -> write pc =================
    {
      f32x4 aR[4], aZ[4], aN[4];
      UNR for (int m = 0; m < 4; ++m) { aR[m] = (f32x4){0,0,0,0}; aZ[m] = aR[m]; aN[m] = aR[m]; }
      #pragma unroll 2
      for (int kt = 0; kt < 8; ++kt) {
        const int k0 = kt * 32 + lg * 8;
        f16x8 Br = *(const f16x8*)(p0base + k0);
        f16x8 Bz = *(const f16x8*)(p0base + 65536 + k0);
        f16x8 Bn = *(const f16x8*)(p0base + 131072 + k0);
        UNR for (int m = 0; m < 4; ++m) {
          f16x8 A = *(const f16x8*)&hall[pa + (m >> 1) * SLOT_ + lswz((m & 1) * 16 + l15, k0)];
          aR[m] = MFMA16(A, Br, aR[m]);
          aZ[m] = MFMA16(A, Bz, aZ[m]);
          aN[m] = MFMA16(A, Bn, aN[m]);
        }
      }
      if (t >= 0) {
        UNR for (int m = 0; m < 4; ++m) {
          const unsigned hsel = (m < 2) ? lo32 : hi32;
          UNR for (int e = 0; e < 4; ++e) {
            const int lrow = (m & 1) * 16 + lg4 + e;
            float fb = (float)((hsel >> ((m & 1) * 16 + lg4 + e)) & 1u);
            float giR = fmaf(fb, dR, sumR0);
            float giZ = fmaf(fb, dZ, sumZ0);
            float giN = fmaf(fb, dN, sumN0);
            float r  = sigm(aR[m][e] + giR);
            float z  = sigm(aZ[m][e] + giZ);
            float n  = tanh_fast(giN + r * (aN[m][e] + bhh0n_c));
            float ho = (float)hall[pa + (m >> 1) * SLOT_ + lswz(lrow, col)];
            hall[pc + (m >> 1) * SLOT_ + lswz(lrow, col)] = (f16)((1.0f - z) * n + z * ho);
          }
        }
      } else {
        UNR for (int m = 0; m < 4; ++m) {
          UNR for (int e = 0; e < 4; ++e) {
            const int lrow = (m & 1) * 16 + lg4 + e;
            float r  = sigm(aR[m][e] + baseR);
            float z  = sigm(aZ[m][e] + baseZ);
            float n  = tanh_fast(baseN + r * (aN[m][e] + bhh0n_c));
            float ho = (float)hall[pa + (m >> 1) * SLOT_ + lswz(lrow, col)];
            hall[pc + (m >> 1) * SLOT_ + lswz(lrow, col)] = (f16)((1.0f - z) * n + z * ho);
          }
        }
      }
    }
    __syncthreads();

    // ================= layer 1: read pc (h0') + pb (h1) -> write pa =================
    {
      // ---- pass 1: r,z gates (ih + hh chained) ----
      f32x4 aR[4], aZ[4];
      UNR for (int m = 0; m < 4; ++m) { aR[m] = (f32x4){0,0,0,0}; aZ[m] = aR[m]; }
      #pragma unroll 2
      for (int kt = 0; kt < 8; ++kt) {
        const int k0 = kt * 32 + lg * 8;
        f16x8 BiR = *(const f16x8*)(pibase + k0);
        f16x8 BiZ = *(const f16x8*)(pibase + 65536 + k0);
        f16x8 BhR = *(const f16x8*)(phbase + k0);
        f16x8 BhZ = *(const f16x8*)(phbase + 65536 + k0);
        UNR for (int m = 0; m < 4; ++m) {
          f16x8 A0 = *(const f16x8*)&hall[pc + (m >> 1) * SLOT_ + lswz((m & 1) * 16 + l15, k0)];
          f16x8 A1 = *(const f16x8*)&hall[pb + (m >> 1) * SLOT_ + lswz((m & 1) * 16 + l15, k0)];
          aR[m] = MFMA16(A0, BiR, aR[m]);  aR[m] = MFMA16(A1, BhR, aR[m]);
          aZ[m] = MFMA16(A0, BiZ, aZ[m]);  aZ[m] = MFMA16(A1, BhZ, aZ[m]);
        }
      }
      f32x4 rv[4], zv[4];
      UNR for (int m = 0; m < 4; ++m)
        UNR for (int e = 0; e < 4; ++e) {
          rv[m][e] = sigm(aR[m][e] + b1r_c);
          zv[m][e] = sigm(aZ[m][e] + b1z_c);
        }
      // ---- pass 2: n gate ----
      f32x4 aNi[4], aNh[4];
      UNR for (int m = 0; m < 4; ++m) { aNi[m] = (f32x4){0,0,0,0}; aNh[m] = aNi[m]; }
      #pragma unroll 2
      for (int kt = 0; kt < 8; ++kt) {
        const int k0 = kt * 32 + lg * 8;
        f16x8 BiN = *(const f16x8*)(pibase + 131072 + k0);
        f16x8 BhN = *(const f16x8*)(phbase + 131072 + k0);
        UNR for (int m = 0; m < 4; ++m) {
          f16x8 A0 = *(const f16x8*)&hall[pc + (m >> 1) * SLOT_ + lswz((m & 1) * 16 + l15, k0)];
          f16x8 A1 = *(const f16x8*)&hall[pb + (m >> 1) * SLOT_ + lswz((m & 1) * 16 + l15, k0)];
          aNi[m] = MFMA16(A0, BiN, aNi[m]);
          aNh[m] = MFMA16(A1, BhN, aNh[m]);
        }
      }
      UNR for (int m = 0; m < 4; ++m) {
        UNR for (int e = 0; e < 4; ++e) {
          const int lrow = (m & 1) * 16 + lg4 + e;
          float n  = tanh_fast(aNi[m][e] + b1ni_c + rv[m][e] * (aNh[m][e] + b1nh_c));
          float z  = zv[m][e];
          float ho = (float)hall[pb + (m >> 1) * SLOT_ + lswz(lrow, col)];
          hall[pa + (m >> 1) * SLOT_ + lswz(lrow, col)] = (f16)((1.0f - z) * n + z * ho);
        }
      }
    }
    __syncthreads();

    // ================= amplitude head (reads pa = h1_new) =================
    if (t >= 0) {
      const int t16 = tid & 15;
      float d0 = 0.f, d1 = 0.f;
      #pragma unroll
      for (int j = 0; j < 2; ++j) {
        const int k0 = t16 * 16 + j * 8;
        f16x8 hv = *(const f16x8*)&hall[pa + (hrow >> 5) * SLOT_ + lswz(hrow & 31, k0)];
        f32x4 w0a = *(const f32x4*)&wampL[k0];
        f32x4 w0b = *(const f32x4*)&wampL[k0 + 4];
        f32x4 w1a = *(const f32x4*)&wampL[256 + k0];
        f32x4 w1b = *(const f32x4*)&wampL[256 + k0 + 4];
        #pragma unroll
        for (int i = 0; i < 4; ++i) {
          float hfa = (float)hv[i], hfb = (float)hv[4 + i];
          d0 = fmaf(hfa, w0a[i], d0); d0 = fmaf(hfb, w0b[i], d0);
          d1 = fmaf(hfa, w1a[i], d1); d1 = fmaf(hfb, w1b[i], d1);
        }
      }
      d0 += __shfl_xor(d0, 1); d0 += __shfl_xor(d0, 2);
      d0 += __shfl_xor(d0, 4); d0 += __shfl_xor(d0, 8);
      d1 += __shfl_xor(d1, 1); d1 += __shfl_xor(d1, 2);
      d1 += __shfl_xor(d1, 4); d1 += __shfl_xor(d1, 8);
      const unsigned hm = hhi ? hi32 : lo32;
      const int bit = (hm >> hsh) & 1;
      float diff = (d0 + ba0) - (d1 + ba1);
      if (bit) diff = -diff;
      prob *= __builtin_amdgcn_rcpf(1.0f + __builtin_amdgcn_exp2f(diff * -1.442695040888963f));
    }

    // rotate pairs: h0_cur := pc, h1_cur := pa, free := pb
    int tmp = pa; pa = pc; pc = pb; pb = tmp;
  }

  if ((tid & 15) == 0) out[rowbase + (tid >> 4)] = sqrtf(prob);
}

extern "C" void kernel_launch(void* const* d_in, const int* in_sizes, int n_in,
                              void* d_out, int out_size, void* d_ws, size_t ws_size,
                              hipStream_t stream) {
  const int*   x     = (const int*)d_in[0];
  const float* w_ih0 = (const float*)d_in[1];
  const float* w_hh0 = (const float*)d_in[2];
  const float* b_ih0 = (const float*)d_in[3];
  const float* b_hh0 = (const float*)d_in[4];
  const float* w_ih1 = (const float*)d_in[5];
  const float* w_hh1 = (const float*)d_in[6];
  const float* b_ih1 = (const float*)d_in[7];
  const float* b_hh1 = (const float*)d_in[8];
  const float* w_amp = (const float*)d_in[9];
  const float* b_amp = (const float*)d_in[10];
  (void)in_sizes; (void)n_in; (void)out_size; (void)ws_size;

  f16* W16 = (f16*)d_ws;   // 3*768*256*2 = 1.18 MB of workspace
  hipLaunchKernelGGL(wcvt, dim3(768), dim3(256), 0, stream, w_hh0, w_ih1, w_hh1, W16);
  hipLaunchKernelGGL(rnnwf, dim3(32768 / TB_), dim3(NT_), 0, stream,
                     x, w_ih0, b_ih0, b_hh0, b_ih1, b_hh1, w_amp, b_amp, W16,
                     (float*)d_out);
}